// Round 1
// baseline (210.778 us; speedup 1.0000x reference)
//
#include <hip/hip_runtime.h>

#define NHID   512
#define NCLS   250
#define CHUNK  200
#define NTOK   2048
#define NOUT   450
#define NPAN   13              // ceil(CHUNK/16) 16-row word panels per class
#define NWB    (NCLS * NPAN)   // 3250 p_words blocks
#define NCB    256             // p_class blocks (128 token tiles x 2 col halves)
#define NBLK   (NWB + NCB)     // 3506
#define NTHR   64              // 1 wave per block: maximize schedulable TLP
#define MAXTOK 64              // binomial(2048,1/250) mean 8.2 — 64 is >>8 sigma safe

typedef __attribute__((ext_vector_type(8))) short bf16x8;
typedef __attribute__((ext_vector_type(4))) float f32x4;

#define MFMA(a, b, c) __builtin_amdgcn_mfma_f32_16x16x32_bf16((a), (b), (c), 0, 0, 0)

__device__ __forceinline__ unsigned hpack(unsigned a, unsigned b) {
    return __builtin_amdgcn_perm(a, b, 0x07060302u);
}

// fp32x8 -> hi/lo split bf16x8 (truncate hi; lo = truncate(exact residual))
__device__ __forceinline__ void cvt8(float4 va, float4 vb, bf16x8& h, bf16x8& l) {
    unsigned u0 = __float_as_uint(va.x), u1 = __float_as_uint(va.y);
    unsigned u2 = __float_as_uint(va.z), u3 = __float_as_uint(va.w);
    unsigned u4 = __float_as_uint(vb.x), u5 = __float_as_uint(vb.y);
    unsigned u6 = __float_as_uint(vb.z), u7 = __float_as_uint(vb.w);
    union { unsigned w[4]; bf16x8 v; } H, L;
    H.w[0] = hpack(u1, u0); H.w[1] = hpack(u3, u2);
    H.w[2] = hpack(u5, u4); H.w[3] = hpack(u7, u6);
    float r0 = va.x - __uint_as_float(u0 & 0xffff0000u);
    float r1 = va.y - __uint_as_float(u1 & 0xffff0000u);
    float r2 = va.z - __uint_as_float(u2 & 0xffff0000u);
    float r3 = va.w - __uint_as_float(u3 & 0xffff0000u);
    float r4 = vb.x - __uint_as_float(u4 & 0xffff0000u);
    float r5 = vb.y - __uint_as_float(u5 & 0xffff0000u);
    float r6 = vb.z - __uint_as_float(u6 & 0xffff0000u);
    float r7 = vb.w - __uint_as_float(u7 & 0xffff0000u);
    L.w[0] = hpack(__float_as_uint(r1), __float_as_uint(r0));
    L.w[1] = hpack(__float_as_uint(r3), __float_as_uint(r2));
    L.w[2] = hpack(__float_as_uint(r5), __float_as_uint(r4));
    L.w[3] = hpack(__float_as_uint(r7), __float_as_uint(r6));
    h = H.v; l = L.v;
}

__device__ __forceinline__ void lds_fence_wave() {
    __builtin_amdgcn_wave_barrier();
    asm volatile("s_waitcnt lgkmcnt(0)" ::: "memory");
    __builtin_amdgcn_wave_barrier();
}

__global__ __launch_bounds__(NTHR)
void cbd_fused(const float* __restrict__ x,  const float* __restrict__ Wc,
               const float* __restrict__ bc, const float* __restrict__ Ww,
               const float* __restrict__ bw, const int* __restrict__ cls_idx,
               float* __restrict__ out)
{
    const int bid  = blockIdx.x;
    const int lane = threadIdx.x;     // 64-thread block = one wave
    const int n    = lane & 15;       // fragment row slot
    const int q    = lane >> 4;       // k-quad

    if (bid >= NWB) {
        // ================= p_class tiles (direct-global, L2-hot Wc) ==========
        const int pcb = bid - NWB;               // 0..255
        const int mt = pcb >> 1, hn = pcb & 1;
        const float* ap = x + (size_t)(mt * 16 + n) * NHID + q * 8;
        #pragma unroll
        for (int g4 = 0; g4 < 2; ++g4) {
            const float* bp[4]; float bias[4]; int col[4]; bool rv[4];
            #pragma unroll
            for (int k = 0; k < 4; ++k) {
                int r = (hn * 8 + g4 * 4 + k) * 16 + n;
                rv[k] = r < NCLS;
                int rc = rv[k] ? r : NCLS - 1;
                bp[k]   = Wc + (size_t)rc * NHID + q * 8;
                bias[k] = bc[rc];
                col[k]  = rc;
            }
            f32x4 acc[4] = {{0,0,0,0},{0,0,0,0},{0,0,0,0},{0,0,0,0}};
            #pragma unroll 2
            for (int s = 0; s < 16; ++s) {
                float4 a0 = *(const float4*)(ap + s * 32);
                float4 a1 = *(const float4*)(ap + s * 32 + 4);
                bf16x8 ah, al; cvt8(a0, a1, ah, al);
                #pragma unroll
                for (int k = 0; k < 4; ++k) {
                    float4 b0 = *(const float4*)(bp[k] + s * 32);
                    float4 b1 = *(const float4*)(bp[k] + s * 32 + 4);
                    bf16x8 bh, bl; cvt8(b0, b1, bh, bl);
                    acc[k] = MFMA(ah, bh, acc[k]);
                    acc[k] = MFMA(al, bh, acc[k]);
                    acc[k] = MFMA(ah, bl, acc[k]);
                }
            }
            #pragma unroll
            for (int k = 0; k < 4; ++k)
                if (rv[k]) {
                    #pragma unroll
                    for (int i = 0; i < 4; ++i)
                        out[(size_t)(mt * 16 + q * 4 + i) * NOUT + col[k]]
                            = acc[k][i] + bias[k];
                }
        }
        return;
    }

    // ================= p_words: one (class, 16-row panel) per wave ===========
    const int c = bid / NPAN;
    const int p = bid - c * NPAN;

    // ---- token membership scan (ballot, deterministic, no atomics) ----
    int myvals[32];
    #pragma unroll
    for (int it = 0; it < 8; ++it) {
        int4 v = *(const int4*)&cls_idx[it * 256 + lane * 4];
        myvals[it*4+0] = v.x; myvals[it*4+1] = v.y;
        myvals[it*4+2] = v.z; myvals[it*4+3] = v.w;
    }
    __shared__ int toktmp[MAXTOK];
    int cnt = 0;
    #pragma unroll
    for (int j = 0; j < 32; ++j) {
        int idx  = (j >> 2) * 256 + lane * 4 + (j & 3);
        bool hit = (myvals[j] == c);
        unsigned long long m = __ballot(hit);
        if (hit) {
            int pos = cnt + (int)__popcll(m & ((1ull << lane) - 1ull));
            if (pos < MAXTOK) toktmp[pos] = idx;
        }
        cnt += (int)__popcll(m);
    }
    if (cnt == 0) return;                       // empty class: skip weight read
    const int cntc = cnt < MAXTOK ? cnt : MAXTOK;
    lds_fence_wave();

    // ---- this wave's 16 word rows ----
    const int r  = p * 16 + n;
    const int rr = r < CHUNK ? r : CHUNK - 1;   // clamp pad rows (store-masked)
    const float* wp  = Ww + ((size_t)c * CHUNK + rr) * NHID + q * 8;
    const float bias = bw[c * CHUNK + rr];

    // ---- token-slot groups (almost always exactly one: mean cnt = 8.2) ----
    for (int sb = 0; sb < cntc; sb += 16) {
        int slot  = sb + n;
        int mytok = toktmp[slot < cntc ? slot : 0];
        int tkS[4]; bool msk[4];
        #pragma unroll
        for (int i = 0; i < 4; ++i) {
            int m = q * 4 + i;
            tkS[i] = __shfl(mytok, m);
            msk[i] = (sb + m) < cntc;
        }
        const float* apx = x + (size_t)mytok * NHID + q * 8;

        f32x4 acc = {0.f, 0.f, 0.f, 0.f};
        #pragma unroll 4
        for (int s = 0; s < 16; ++s) {
            float4 a0 = *(const float4*)(apx + s * 32);
            float4 a1 = *(const float4*)(apx + s * 32 + 4);
            float4 b0 = *(const float4*)(wp + s * 32);
            float4 b1 = *(const float4*)(wp + s * 32 + 4);
            bf16x8 ah, al, bh, bl;
            cvt8(a0, a1, ah, al);
            cvt8(b0, b1, bh, bl);
            acc = MFMA(ah, bh, acc);
            acc = MFMA(al, bh, acc);
            acc = MFMA(ah, bl, acc);
        }

        if (r < CHUNK) {
            #pragma unroll
            for (int i = 0; i < 4; ++i)
                if (msk[i])
                    out[(size_t)tkS[i] * NOUT + NCLS + r] = acc[i] + bias;
        }
    }
}

extern "C" void kernel_launch(void* const* d_in, const int* in_sizes, int n_in,
                              void* d_out, int out_size, void* d_ws, size_t ws_size,
                              hipStream_t stream) {
    const float* x   = (const float*)d_in[0];
    const float* Wc  = (const float*)d_in[1];
    const float* bc  = (const float*)d_in[2];
    const float* Ww  = (const float*)d_in[3];
    const float* bw  = (const float*)d_in[4];
    const int*   cls = (const int*)d_in[5];
    float* out = (float*)d_out;
    hipLaunchKernelGGL(cbd_fused, dim3(NBLK), dim3(NTHR), 0, stream,
                       x, Wc, bc, Ww, bw, cls, out);
}

// Round 2
// 174.421 us; speedup vs baseline: 1.2084x; 1.2084x over previous
//
#include <hip/hip_runtime.h>

#define NHID   512
#define NCLS   250
#define CHUNK  200
#define NTOK   2048
#define NOUT   450
#define NPAN   13              // ceil(CHUNK/16) 16-row word panels per class
#define NWB    (NCLS * NPAN)   // 3250 p_words blocks
#define NCB    256             // p_class blocks (dispatched FIRST: they are long)
#define NBLK   (NWB + NCB)     // 3506
#define NTHR   64              // 1 wave per block
#define MAXTOK 64

typedef __attribute__((ext_vector_type(8))) short bf16x8;
typedef __attribute__((ext_vector_type(4))) float f32x4;

#define MFMA(a, b, c) __builtin_amdgcn_mfma_f32_16x16x32_bf16((a), (b), (c), 0, 0, 0)

__device__ __forceinline__ unsigned hpack(unsigned a, unsigned b) {
    return __builtin_amdgcn_perm(a, b, 0x07060302u);
}

// fp32x8 -> hi/lo split bf16x8 (truncate hi; lo = truncate(exact residual))
__device__ __forceinline__ void cvt8(float4 va, float4 vb, bf16x8& h, bf16x8& l) {
    unsigned u0 = __float_as_uint(va.x), u1 = __float_as_uint(va.y);
    unsigned u2 = __float_as_uint(va.z), u3 = __float_as_uint(va.w);
    unsigned u4 = __float_as_uint(vb.x), u5 = __float_as_uint(vb.y);
    unsigned u6 = __float_as_uint(vb.z), u7 = __float_as_uint(vb.w);
    union { unsigned w[4]; bf16x8 v; } H, L;
    H.w[0] = hpack(u1, u0); H.w[1] = hpack(u3, u2);
    H.w[2] = hpack(u5, u4); H.w[3] = hpack(u7, u6);
    float r0 = va.x - __uint_as_float(u0 & 0xffff0000u);
    float r1 = va.y - __uint_as_float(u1 & 0xffff0000u);
    float r2 = va.z - __uint_as_float(u2 & 0xffff0000u);
    float r3 = va.w - __uint_as_float(u3 & 0xffff0000u);
    float r4 = vb.x - __uint_as_float(u4 & 0xffff0000u);
    float r5 = vb.y - __uint_as_float(u5 & 0xffff0000u);
    float r6 = vb.z - __uint_as_float(u6 & 0xffff0000u);
    float r7 = vb.w - __uint_as_float(u7 & 0xffff0000u);
    L.w[0] = hpack(__float_as_uint(r1), __float_as_uint(r0));
    L.w[1] = hpack(__float_as_uint(r3), __float_as_uint(r2));
    L.w[2] = hpack(__float_as_uint(r5), __float_as_uint(r4));
    L.w[3] = hpack(__float_as_uint(r7), __float_as_uint(r6));
    h = H.v; l = L.v;
}

__device__ __forceinline__ void lds_fence_wave() {
    __builtin_amdgcn_wave_barrier();
    asm volatile("s_waitcnt lgkmcnt(0)" ::: "memory");
    __builtin_amdgcn_wave_barrier();
}

__global__ __launch_bounds__(NTHR, 3)
void cbd_fused(const float* __restrict__ x,  const float* __restrict__ Wc,
               const float* __restrict__ bc, const float* __restrict__ Ww,
               const float* __restrict__ bw, const int* __restrict__ cls_idx,
               float* __restrict__ out)
{
    const int bid  = blockIdx.x;
    const int lane = threadIdx.x;     // 64-thread block = one wave
    const int n    = lane & 15;       // fragment row slot
    const int q    = lane >> 4;       // k-quad

    if (bid < NCB) {
        // ======== p_class tiles (L2-hot Wc), 2-deep register pipeline ========
        const int mt = bid >> 1, hn = bid & 1;
        const float* ap = x + (size_t)(mt * 16 + n) * NHID + q * 8;
        #pragma unroll
        for (int g4 = 0; g4 < 2; ++g4) {
            const float* bp[4]; float bias[4]; int col[4]; bool rv[4];
            #pragma unroll
            for (int k = 0; k < 4; ++k) {
                int r = (hn * 8 + g4 * 4 + k) * 16 + n;
                rv[k] = r < NCLS;
                int rc = rv[k] ? r : NCLS - 1;
                bp[k]   = Wc + (size_t)rc * NHID + q * 8;
                bias[k] = bc[rc];
                col[k]  = rc;
            }
            f32x4 acc[4] = {{0,0,0,0},{0,0,0,0},{0,0,0,0},{0,0,0,0}};
            // register double-buffer: chunk = 1 k-step (A pair + 4 B pairs)
            float4 qa[2][2], qb[2][8];
            #pragma unroll
            for (int j = 0; j < 2; ++j) {
                qa[j][0] = *(const float4*)(ap + j * 32);
                qa[j][1] = *(const float4*)(ap + j * 32 + 4);
                #pragma unroll
                for (int k = 0; k < 4; ++k) {
                    qb[j][2*k]   = *(const float4*)(bp[k] + j * 32);
                    qb[j][2*k+1] = *(const float4*)(bp[k] + j * 32 + 4);
                }
            }
            #pragma unroll 2
            for (int s = 0; s < 16; ++s) {
                const int b = s & 1;   // compile-time within unroll-2 body
                bf16x8 ah, al; cvt8(qa[b][0], qa[b][1], ah, al);
                #pragma unroll
                for (int k = 0; k < 4; ++k) {
                    bf16x8 bh, bl; cvt8(qb[b][2*k], qb[b][2*k+1], bh, bl);
                    acc[k] = MFMA(ah, bh, acc[k]);
                    acc[k] = MFMA(al, bh, acc[k]);
                    acc[k] = MFMA(ah, bl, acc[k]);
                }
                if (s + 2 < 16) {
                    qa[b][0] = *(const float4*)(ap + (s+2) * 32);
                    qa[b][1] = *(const float4*)(ap + (s+2) * 32 + 4);
                    #pragma unroll
                    for (int k = 0; k < 4; ++k) {
                        qb[b][2*k]   = *(const float4*)(bp[k] + (s+2) * 32);
                        qb[b][2*k+1] = *(const float4*)(bp[k] + (s+2) * 32 + 4);
                    }
                }
            }
            #pragma unroll
            for (int k = 0; k < 4; ++k)
                if (rv[k]) {
                    #pragma unroll
                    for (int i = 0; i < 4; ++i)
                        out[(size_t)(mt * 16 + q * 4 + i) * NOUT + col[k]]
                            = acc[k][i] + bias[k];
                }
        }
        return;
    }

    // ================= p_words: one (class, 16-row panel) per wave ===========
    const int wb = bid - NCB;
    const int c = wb / NPAN;
    const int p = wb - c * NPAN;

    const int r  = p * 16 + n;
    const int rr = r < CHUNK ? r : CHUNK - 1;   // clamp pad rows (store-masked)
    const float* wp = Ww + ((size_t)c * CHUNK + rr) * NHID + q * 8;

    // ---- issue B chunks 0,1 NOW (address depends only on bid) — the ballot
    //      scan below overlaps their miss latency. chunk = 2 k-steps = 4 KB.
    float4 pb[2][4];
    #pragma unroll
    for (int j = 0; j < 2; ++j)
        #pragma unroll
        for (int t = 0; t < 2; ++t) {
            pb[j][2*t]   = *(const float4*)(wp + (2*j + t) * 32);
            pb[j][2*t+1] = *(const float4*)(wp + (2*j + t) * 32 + 4);
        }

    // ---- token membership scan (ballot, deterministic, no atomics) ----
    int myvals[32];
    #pragma unroll
    for (int it = 0; it < 8; ++it) {
        int4 v = *(const int4*)&cls_idx[it * 256 + lane * 4];
        myvals[it*4+0] = v.x; myvals[it*4+1] = v.y;
        myvals[it*4+2] = v.z; myvals[it*4+3] = v.w;
    }
    __shared__ int toktmp[MAXTOK];
    int cnt = 0;
    #pragma unroll
    for (int j = 0; j < 32; ++j) {
        int idx  = (j >> 2) * 256 + lane * 4 + (j & 3);
        bool hit = (myvals[j] == c);
        unsigned long long m = __ballot(hit);
        if (hit) {
            int pos = cnt + (int)__popcll(m & ((1ull << lane) - 1ull));
            if (pos < MAXTOK) toktmp[pos] = idx;
        }
        cnt += (int)__popcll(m);
    }
    if (cnt == 0) return;                       // empty class (P ~ e^-8.2)
    const int cntc = cnt < MAXTOK ? cnt : MAXTOK;
    lds_fence_wave();

    const float bias = bw[c * CHUNK + rr];

    // ---- token-slot groups (almost always exactly one: mean cnt = 8.2) ----
    for (int sb = 0; sb < cntc; sb += 16) {
        int slot  = sb + n;
        int mytok = toktmp[slot < cntc ? slot : 0];
        int tkS[4]; bool msk[4];
        #pragma unroll
        for (int i = 0; i < 4; ++i) {
            int m = q * 4 + i;
            tkS[i] = __shfl(mytok, m);
            msk[i] = (sb + m) < cntc;
        }
        const float* apx = x + (size_t)mytok * NHID + q * 8;

        // A chunks 0,1 (token-dependent, issue as soon as tokens known)
        float4 pa[2][4];
        #pragma unroll
        for (int j = 0; j < 2; ++j)
            #pragma unroll
            for (int t = 0; t < 2; ++t) {
                pa[j][2*t]   = *(const float4*)(apx + (2*j + t) * 32);
                pa[j][2*t+1] = *(const float4*)(apx + (2*j + t) * 32 + 4);
            }
        if (sb > 0) {   // B chunks were consumed by the previous slot group
            #pragma unroll
            for (int j = 0; j < 2; ++j)
                #pragma unroll
                for (int t = 0; t < 2; ++t) {
                    pb[j][2*t]   = *(const float4*)(wp + (2*j + t) * 32);
                    pb[j][2*t+1] = *(const float4*)(wp + (2*j + t) * 32 + 4);
                }
        }

        f32x4 acc = {0.f, 0.f, 0.f, 0.f};
        #pragma unroll 2
        for (int j = 0; j < 8; ++j) {          // 8 chunks x 2 k-steps
            const int b = j & 1;               // compile-time within unroll-2
            #pragma unroll
            for (int t = 0; t < 2; ++t) {
                bf16x8 ah, al, bh, bl;
                cvt8(pa[b][2*t], pa[b][2*t+1], ah, al);
                cvt8(pb[b][2*t], pb[b][2*t+1], bh, bl);
                acc = MFMA(ah, bh, acc);
                acc = MFMA(al, bh, acc);
                acc = MFMA(ah, bl, acc);
            }
            if (j + 2 < 8) {                   // refill buffer b with chunk j+2
                #pragma unroll
                for (int t = 0; t < 2; ++t) {
                    const int s = 2 * (j + 2) + t;
                    pa[b][2*t]   = *(const float4*)(apx + s * 32);
                    pa[b][2*t+1] = *(const float4*)(apx + s * 32 + 4);
                    pb[b][2*t]   = *(const float4*)(wp + s * 32);
                    pb[b][2*t+1] = *(const float4*)(wp + s * 32 + 4);
                }
            }
        }

        if (r < CHUNK) {
            #pragma unroll
            for (int i = 0; i < 4; ++i)
                if (msk[i])
                    out[(size_t)tkS[i] * NOUT + NCLS + r] = acc[i] + bias;
        }
    }
}

extern "C" void kernel_launch(void* const* d_in, const int* in_sizes, int n_in,
                              void* d_out, int out_size, void* d_ws, size_t ws_size,
                              hipStream_t stream) {
    const float* x   = (const float*)d_in[0];
    const float* Wc  = (const float*)d_in[1];
    const float* bc  = (const float*)d_in[2];
    const float* Ww  = (const float*)d_in[3];
    const float* bw  = (const float*)d_in[4];
    const int*   cls = (const int*)d_in[5];
    float* out = (float*)d_out;
    hipLaunchKernelGGL(cbd_fused, dim3(NBLK), dim3(NTHR), 0, stream,
                       x, Wc, bc, Ww, bw, cls, out);
}